// Round 1
// baseline (413.807 us; speedup 1.0000x reference)
//
#include <hip/hip_runtime.h>
#include <hip/hip_bf16.h>
#include <math.h>

// Problem constants (match reference)
#define T_   4096
#define B_   4
#define C_   256
#define C3_  768
#define H_   1024
#define E_   4
#define M_   (B_*T_)      // 16384 rows
#define NCH_ 16
#define CHL_ (T_/NCH_)    // 256

typedef __attribute__((ext_vector_type(8))) short short8;
typedef __attribute__((ext_vector_type(4))) float floatx4;

__device__ __forceinline__ float b2f(unsigned short u) {
  union { unsigned int i; float f; } x; x.i = ((unsigned int)u) << 16; return x.f;
}
__device__ __forceinline__ unsigned short f2b(float f) {
  __hip_bfloat16 h = __float2bfloat16(f);
  return *reinterpret_cast<unsigned short*>(&h);
}

// ---------------- transpose + fp32->bf16 convert: src[K,N] -> dst[N,K] ----------------
__global__ __launch_bounds__(256) void transpose_cvt(
    const float* __restrict__ src, unsigned short* __restrict__ dst, int K, int N) {
  __shared__ float tile[32][33];
  const float* s = src + (size_t)blockIdx.z * K * N;
  unsigned short* d = dst + (size_t)blockIdx.z * K * N;
  int n0 = blockIdx.x * 32, k0 = blockIdx.y * 32;
  int tx = threadIdx.x, ty = threadIdx.y;   // blockDim (32,8)
  #pragma unroll
  for (int i = 0; i < 32; i += 8)
    tile[ty + i][tx] = s[(size_t)(k0 + ty + i) * N + n0 + tx];
  __syncthreads();
  #pragma unroll
  for (int i = 0; i < 32; i += 8)
    d[(size_t)(n0 + ty + i) * K + k0 + tx] = f2b(tile[tx][ty + i]);
}

// ---------------- LayerNorm 1: x -> h (bf16) ----------------
__global__ __launch_bounds__(256) void ln1_kernel(
    const float* __restrict__ x, const float* __restrict__ g,
    const float* __restrict__ b, unsigned short* __restrict__ h) {
  __shared__ float red[4];
  int row = blockIdx.x, tid = threadIdx.x;
  float v = x[(size_t)row * C_ + tid];
  float s = v;
  #pragma unroll
  for (int o = 32; o; o >>= 1) s += __shfl_xor(s, o);
  if ((tid & 63) == 0) red[tid >> 6] = s;
  __syncthreads();
  float mean = (red[0] + red[1] + red[2] + red[3]) * (1.0f / C_);
  __syncthreads();
  float d = v - mean;
  float q = d * d;
  #pragma unroll
  for (int o = 32; o; o >>= 1) q += __shfl_xor(q, o);
  if ((tid & 63) == 0) red[tid >> 6] = q;
  __syncthreads();
  float var = (red[0] + red[1] + red[2] + red[3]) * (1.0f / C_);
  float out = d * rsqrtf(var + 1e-5f) * g[tid] + b[tid];
  h[(size_t)row * C_ + tid] = f2b(out);
}

// ---------------- LayerNorm 2 + gating softmax ----------------
__global__ __launch_bounds__(256) void ln2_gates_kernel(
    const float* __restrict__ x1, const float* __restrict__ g,
    const float* __restrict__ b, const float* __restrict__ gw,
    const float* __restrict__ gb, unsigned short* __restrict__ h2,
    float* __restrict__ gates) {
  __shared__ float red[4];
  __shared__ float redg[4][4];
  int row = blockIdx.x, tid = threadIdx.x;
  float v = x1[(size_t)row * C_ + tid];
  float s = v;
  #pragma unroll
  for (int o = 32; o; o >>= 1) s += __shfl_xor(s, o);
  if ((tid & 63) == 0) red[tid >> 6] = s;
  __syncthreads();
  float mean = (red[0] + red[1] + red[2] + red[3]) * (1.0f / C_);
  __syncthreads();
  float d = v - mean;
  float q = d * d;
  #pragma unroll
  for (int o = 32; o; o >>= 1) q += __shfl_xor(q, o);
  if ((tid & 63) == 0) red[tid >> 6] = q;
  __syncthreads();
  float var = (red[0] + red[1] + red[2] + red[3]) * (1.0f / C_);
  float hv = d * rsqrtf(var + 1e-5f) * g[tid] + b[tid];
  h2[(size_t)row * C_ + tid] = f2b(hv);
  // gating: logits[e] = sum_c hv[c]*gw[c][e] + gb[e]; softmax over E_=4
  float p0 = hv * gw[tid * 4 + 0];
  float p1 = hv * gw[tid * 4 + 1];
  float p2 = hv * gw[tid * 4 + 2];
  float p3 = hv * gw[tid * 4 + 3];
  #pragma unroll
  for (int o = 32; o; o >>= 1) {
    p0 += __shfl_xor(p0, o); p1 += __shfl_xor(p1, o);
    p2 += __shfl_xor(p2, o); p3 += __shfl_xor(p3, o);
  }
  if ((tid & 63) == 0) {
    int w = tid >> 6;
    redg[w][0] = p0; redg[w][1] = p1; redg[w][2] = p2; redg[w][3] = p3;
  }
  __syncthreads();
  if (tid == 0) {
    float t4[4];
    #pragma unroll
    for (int e = 0; e < 4; e++)
      t4[e] = redg[0][e] + redg[1][e] + redg[2][e] + redg[3][e] + gb[e];
    float m = fmaxf(fmaxf(t4[0], t4[1]), fmaxf(t4[2], t4[3]));
    float zs = 0.f;
    #pragma unroll
    for (int e = 0; e < 4; e++) { t4[e] = __expf(t4[e] - m); zs += t4[e]; }
    float inv = 1.0f / zs;
    #pragma unroll
    for (int e = 0; e < 4; e++) gates[(size_t)row * 4 + e] = t4[e] * inv;
  }
}

// ---------------- chunked prefix scan of v (inside qkv buffer, cols 512..767) ----------------
__global__ __launch_bounds__(256) void scan1_kernel(const unsigned short* __restrict__ qkv,
                                                    float* __restrict__ S) {
  int b = blockIdx.x >> 4, ch = blockIdx.x & 15, c = threadIdx.x;
  float s = 0.f;
  size_t base = ((size_t)b * T_ + (size_t)ch * CHL_) * C3_ + 512 + c;
  for (int t = 0; t < CHL_; t++) s += b2f(qkv[base + (size_t)t * C3_]);
  S[((size_t)b * NCH_ + ch) * C_ + c] = s;
}
__global__ __launch_bounds__(256) void scan2_kernel(float* __restrict__ S) {
  int b = blockIdx.x, c = threadIdx.x;
  float run = 0.f;
  for (int ch = 0; ch < NCH_; ch++) {
    size_t i = ((size_t)b * NCH_ + ch) * C_ + c;
    float t = S[i]; S[i] = run; run += t;
  }
}
__global__ __launch_bounds__(256) void scan3_kernel(const unsigned short* __restrict__ qkv,
                                                    const float* __restrict__ S,
                                                    float* __restrict__ P) {
  int b = blockIdx.x >> 4, ch = blockIdx.x & 15, c = threadIdx.x;
  float run = S[((size_t)b * NCH_ + ch) * C_ + c];
  size_t row0 = (size_t)b * T_ + (size_t)ch * CHL_;
  for (int t = 0; t < CHL_; t++) {
    run += b2f(qkv[(row0 + t) * C3_ + 512 + c]);
    P[(row0 + t) * C_ + c] = run;
  }
}

// ---------------- windowed attention, wave per row ----------------
// a_out[i] = gate * (sum_{j in [i-16,i]} e^{s_ij - m} v_j + e^{-m} P[i-17]) / Z
// Z = sum_win e^{s - m} + e^{-m} * max(0, t-16)
__global__ __launch_bounds__(256) void attn_kernel(
    const unsigned short* __restrict__ qkv, const float* __restrict__ P,
    const float* __restrict__ gate, unsigned short* __restrict__ aout) {
  int wave = threadIdx.x >> 6, lane = threadIdx.x & 63;
  int r = blockIdx.x * 4 + wave;        // global row
  int t = r & (T_ - 1);
  const unsigned short* qp = qkv + (size_t)r * C3_ + lane * 4;
  ushort4 qu = *(const ushort4*)qp;
  float q0 = b2f(qu.x), q1 = b2f(qu.y), q2 = b2f(qu.z), q3 = b2f(qu.w);
  float sv[17];
  float smax = -1e30f;
  #pragma unroll
  for (int j = 0; j < 17; j++) {
    int jj = t - 16 + j;
    float d = 0.f;
    if (jj >= 0) {
      ushort4 ku = *(const ushort4*)(qkv + (size_t)(r - 16 + j) * C3_ + 256 + lane * 4);
      d = q0 * b2f(ku.x) + q1 * b2f(ku.y) + q2 * b2f(ku.z) + q3 * b2f(ku.w);
    }
    #pragma unroll
    for (int o = 32; o; o >>= 1) d += __shfl_xor(d, o);
    sv[j] = d * 0.0625f;                // / sqrt(256)
    if (jj >= 0) smax = fmaxf(smax, sv[j]);
  }
  if (t > 16) smax = fmaxf(smax, 0.0f); // out-of-window entries have score 0
  float Z = 0.f, n0 = 0.f, n1 = 0.f, n2 = 0.f, n3 = 0.f;
  #pragma unroll
  for (int j = 0; j < 17; j++) {
    int jj = t - 16 + j;
    if (jj >= 0) {
      float e = __expf(sv[j] - smax);
      Z += e;
      ushort4 vu = *(const ushort4*)(qkv + (size_t)(r - 16 + j) * C3_ + 512 + lane * 4);
      n0 += e * b2f(vu.x); n1 += e * b2f(vu.y); n2 += e * b2f(vu.z); n3 += e * b2f(vu.w);
    }
  }
  if (t > 16) {
    float e0 = __expf(-smax);
    Z += e0 * (float)(t - 16);
    const float* pp = P + (size_t)(r - 17) * C_ + lane * 4;
    n0 += e0 * pp[0]; n1 += e0 * pp[1]; n2 += e0 * pp[2]; n3 += e0 * pp[3];
  }
  float inv = 1.0f / Z;
  const float* gp = gate + lane * 4;
  ushort4 o;
  o.x = f2b(n0 * inv * gp[0]); o.y = f2b(n1 * inv * gp[1]);
  o.z = f2b(n2 * inv * gp[2]); o.w = f2b(n3 * inv * gp[3]);
  *(ushort4*)(aout + (size_t)r * C_ + lane * 4) = o;
}

// ---------------- bf16 MFMA GEMM: C = A[M,K] @ B[K,N] (+ epilogue) ----------------
// A row-major bf16; Bt is B transposed [N,K] row-major bf16.
// EPI 0: outb = bf16(acc + bias)                             (qkv)
// EPI 1: t = acc + bias + resid; outf = t; outf2 = t         (proj: x1 and d_out)
// EPI 2: outb = bf16(gelu_exact(acc + bias))                 (MoE up)
// EPI 3: outf += gates[row][expert] * (acc + bias)           (MoE down accumulate)
template<int EPI>
__global__ __launch_bounds__(256) void gemm64(
    const unsigned short* __restrict__ A, const unsigned short* __restrict__ Bt,
    const float* __restrict__ bias, int N, int K,
    const float* __restrict__ resid, float* __restrict__ outf,
    float* __restrict__ outf2, unsigned short* __restrict__ outb,
    const float* __restrict__ gates, int expert) {
  __shared__ unsigned short As[64][72];   // +8 pad: 16B-aligned rows, 2-way-max bank aliasing
  __shared__ unsigned short Bs[64][72];
  const int tid = threadIdx.x;
  const int wave = tid >> 6, lane = tid & 63;
  const int mBlk = blockIdx.x * 64, nBlk = blockIdx.y * 64;
  const int wm = (wave >> 1) * 32, wn = (wave & 1) * 32;
  floatx4 acc[2][2];
  #pragma unroll
  for (int i = 0; i < 2; i++)
    #pragma unroll
    for (int j = 0; j < 2; j++) acc[i][j] = (floatx4){0.f, 0.f, 0.f, 0.f};

  const int ldRow = tid >> 2;         // 0..63
  const int ldSeg = (tid & 3) * 16;   // 0,16,32,48 (elements)
  const int lm = lane & 15, lk = (lane >> 4) * 8;

  for (int kt = 0; kt < K; kt += 64) {
    const unsigned short* ga = A + (size_t)(mBlk + ldRow) * K + kt + ldSeg;
    const unsigned short* gb = Bt + (size_t)(nBlk + ldRow) * K + kt + ldSeg;
    uint4 a0 = *(const uint4*)ga;
    uint4 a1 = *(const uint4*)(ga + 8);
    uint4 b0 = *(const uint4*)gb;
    uint4 b1 = *(const uint4*)(gb + 8);
    __syncthreads();
    *(uint4*)&As[ldRow][ldSeg]     = a0;
    *(uint4*)&As[ldRow][ldSeg + 8] = a1;
    *(uint4*)&Bs[ldRow][ldSeg]     = b0;
    *(uint4*)&Bs[ldRow][ldSeg + 8] = b1;
    __syncthreads();
    #pragma unroll
    for (int kk = 0; kk < 64; kk += 32) {
      short8 af[2], bf[2];
      af[0] = *(const short8*)&As[wm + lm][kk + lk];
      af[1] = *(const short8*)&As[wm + 16 + lm][kk + lk];
      bf[0] = *(const short8*)&Bs[wn + lm][kk + lk];
      bf[1] = *(const short8*)&Bs[wn + 16 + lm][kk + lk];
      #pragma unroll
      for (int i = 0; i < 2; i++)
        #pragma unroll
        for (int j = 0; j < 2; j++)
          acc[i][j] = __builtin_amdgcn_mfma_f32_16x16x32_bf16(af[i], bf[j], acc[i][j], 0, 0, 0);
    }
  }
  // epilogue: C/D layout col = lane&15, row = (lane>>4)*4 + reg
  const int lc = lane & 15, lr4 = (lane >> 4) * 4;
  #pragma unroll
  for (int i = 0; i < 2; i++) {
    #pragma unroll
    for (int j = 0; j < 2; j++) {
      int col = nBlk + wn + j * 16 + lc;
      float bs = bias[col];
      #pragma unroll
      for (int rr = 0; rr < 4; rr++) {
        int row = mBlk + wm + i * 16 + lr4 + rr;
        size_t idx = (size_t)row * N + col;
        float val = acc[i][j][rr] + bs;
        if (EPI == 0) {
          outb[idx] = f2b(val);
        } else if (EPI == 1) {
          float tv = val + resid[idx];
          outf[idx] = tv;
          outf2[idx] = tv;
        } else if (EPI == 2) {
          float ge = 0.5f * val * (1.0f + erff(val * 0.70710678118f));
          outb[idx] = f2b(ge);
        } else {
          float gv = gates[(size_t)row * E_ + expert];
          outf[idx] += gv * val;
        }
      }
    }
  }
}

extern "C" void kernel_launch(void* const* d_in, const int* in_sizes, int n_in,
                              void* d_out, int out_size, void* d_ws, size_t ws_size,
                              hipStream_t stream) {
  const float* x       = (const float*)d_in[0];
  const float* ln1_g   = (const float*)d_in[1];
  const float* ln1_b   = (const float*)d_in[2];
  const float* qkv_w   = (const float*)d_in[3];
  const float* qkv_b   = (const float*)d_in[4];
  const float* proj_w  = (const float*)d_in[5];
  const float* proj_b  = (const float*)d_in[6];
  const float* attn_g  = (const float*)d_in[7];
  const float* ln2_g   = (const float*)d_in[8];
  const float* ln2_b   = (const float*)d_in[9];
  const float* gat_w   = (const float*)d_in[10];
  const float* gat_b   = (const float*)d_in[11];
  const float* e_w1    = (const float*)d_in[12];
  const float* e_b1    = (const float*)d_in[13];
  const float* e_w2    = (const float*)d_in[14];
  const float* e_b2    = (const float*)d_in[15];
  float* out = (float*)d_out;

  // workspace carve (≈117 MB)
  char* p = (char*)d_ws;
  unsigned short* h    = (unsigned short*)p; p += (size_t)M_ * C_ * 2;    // 8 MB
  unsigned short* qkv  = (unsigned short*)p; p += (size_t)M_ * C3_ * 2;   // 24 MB
  float*          P    = (float*)p;          p += (size_t)M_ * C_ * 4;    // 16 MB
  unsigned short* aout = (unsigned short*)p; p += (size_t)M_ * C_ * 2;    // 8 MB
  float*          x1   = (float*)p;          p += (size_t)M_ * C_ * 4;    // 16 MB
  unsigned short* h2   = (unsigned short*)p; p += (size_t)M_ * C_ * 2;    // 8 MB
  float*          gts  = (float*)p;          p += (size_t)M_ * E_ * 4;    // 0.25 MB
  unsigned short* hid  = (unsigned short*)p; p += (size_t)M_ * H_ * 2;    // 32 MB
  float*          S    = (float*)p;          p += (size_t)B_ * NCH_ * C_ * 4;
  unsigned short* wq   = (unsigned short*)p; p += (size_t)C3_ * C_ * 2;
  unsigned short* wp   = (unsigned short*)p; p += (size_t)C_ * C_ * 2;
  unsigned short* w1t  = (unsigned short*)p; p += (size_t)E_ * H_ * C_ * 2;
  unsigned short* w2t  = (unsigned short*)p; p += (size_t)E_ * C_ * H_ * 2;

  dim3 t32x8(32, 8);
  // weight transpose+convert to bf16 [N,K]
  transpose_cvt<<<dim3(C3_/32, C_/32, 1), t32x8, 0, stream>>>(qkv_w, wq, C_, C3_);
  transpose_cvt<<<dim3(C_/32, C_/32, 1),  t32x8, 0, stream>>>(proj_w, wp, C_, C_);
  transpose_cvt<<<dim3(H_/32, C_/32, E_), t32x8, 0, stream>>>(e_w1, w1t, C_, H_);
  transpose_cvt<<<dim3(C_/32, H_/32, E_), t32x8, 0, stream>>>(e_w2, w2t, H_, C_);

  // LN1
  ln1_kernel<<<M_, 256, 0, stream>>>(x, ln1_g, ln1_b, h);
  // qkv = h @ qkv_w + qkv_b  -> bf16 [M, 768]
  gemm64<0><<<dim3(M_/64, C3_/64), 256, 0, stream>>>(h, wq, qkv_b, C3_, C_,
      nullptr, nullptr, nullptr, qkv, nullptr, 0);
  // prefix sums of v
  scan1_kernel<<<B_*NCH_, 256, 0, stream>>>(qkv, S);
  scan2_kernel<<<B_, 256, 0, stream>>>(S);
  scan3_kernel<<<B_*NCH_, 256, 0, stream>>>(qkv, S, P);
  // windowed attention (+ attn_gate) -> aout bf16
  attn_kernel<<<M_/4, 256, 0, stream>>>(qkv, P, attn_g, aout);
  // x1 = x + aout @ proj_w + proj_b ; also seed d_out = x1
  gemm64<1><<<dim3(M_/64, C_/64), 256, 0, stream>>>(aout, wp, proj_b, C_, C_,
      x, x1, out, nullptr, nullptr, 0);
  // LN2 + gating softmax
  ln2_gates_kernel<<<M_, 256, 0, stream>>>(x1, ln2_g, ln2_b, gat_w, gat_b, h2, gts);
  // dense MoE, experts sequential: hid = gelu(h2@w1+b1); out += gate_e*(hid@w2+b2)
  for (int e = 0; e < E_; e++) {
    gemm64<2><<<dim3(M_/64, H_/64), 256, 0, stream>>>(h2, w1t + (size_t)e * H_ * C_,
        e_b1 + (size_t)e * H_, H_, C_, nullptr, nullptr, nullptr, hid, nullptr, 0);
    gemm64<3><<<dim3(M_/64, C_/64), 256, 0, stream>>>(hid, w2t + (size_t)e * C_ * H_,
        e_b2 + (size_t)e * C_, C_, H_, nullptr, out, nullptr, nullptr, gts, e);
  }
}